// Round 4
// baseline (526.173 us; speedup 1.0000x reference)
//
#include <hip/hip_runtime.h>

// Problem constants
#define LSEQ 2048
#define DMODEL 512
#define DHD 64          // head dim of the (faithful) raw view
#define SLAB (LSEQ*DHD) // 131072 elements per contiguous head slab

typedef __attribute__((ext_vector_type(8))) short short8;
typedef __attribute__((ext_vector_type(4))) float f32x4;

__device__ __forceinline__ short f2bf(float x) {   // round-to-nearest-even bf16
    union { float f; unsigned u; } v; v.f = x;
    unsigned r = v.u + 0x7FFF + ((v.u >> 16) & 1);
    return (short)(r >> 16);
}
__device__ __forceinline__ float bf2f(short h) {
    union { float f; unsigned u; } v; v.u = ((unsigned)(unsigned short)h) << 16;
    return v.f;
}

// ---------------------------------------------------------------------------
// Projection GEMM: C[8192,512] = A[8192,512] @ W[512,512]^T + bias
// MODE 0: write f32 Cf; MODE 1: write split hi/lo bf16 (C0,C1); MODE 2: bf16 C0
// Split-f32 precision: a*w ~= ah*wh + ah*wl + al*wh  (3 MFMAs)
// ---------------------------------------------------------------------------
template<int MODE>
__global__ __launch_bounds__(256) void proj_gemm(
    const float* __restrict__ A, const float* __restrict__ W,
    const float* __restrict__ bias, float* __restrict__ Cf,
    short* __restrict__ C0, short* __restrict__ C1)
{
    __shared__ __align__(16) short Ah[64][40], Al[64][40], Bh[64][40], Bl[64][40];

    const int tid  = threadIdx.x;
    const int lane = tid & 63, wv = tid >> 6;
    const int wm = wv >> 1, wn = wv & 1;
    const int fr = lane & 15, kg = lane >> 4;
    const int m0 = blockIdx.y * 64, n0 = blockIdx.x * 64;

    f32x4 acc[2][2];
    #pragma unroll
    for (int i = 0; i < 2; ++i)
        #pragma unroll
        for (int j = 0; j < 2; ++j) { f32x4 z = {0.f,0.f,0.f,0.f}; acc[i][j] = z; }

    const int srow = tid >> 2, sc8 = (tid & 3) << 3;

    for (int kt = 0; kt < 16; ++kt) {
        __syncthreads();
        {   // stage A/W tile, converting f32 -> hi/lo bf16
            const float* ap = A + (size_t)(m0 + srow) * DMODEL + kt*32 + sc8;
            float4 a0 = *(const float4*)ap;
            float4 a1 = *(const float4*)(ap + 4);
            float va[8] = {a0.x,a0.y,a0.z,a0.w,a1.x,a1.y,a1.z,a1.w};
            short8 h, l;
            #pragma unroll
            for (int j = 0; j < 8; ++j) { short hh = f2bf(va[j]); h[j] = hh; l[j] = f2bf(va[j] - bf2f(hh)); }
            *(short8*)&Ah[srow][sc8] = h; *(short8*)&Al[srow][sc8] = l;

            const float* wp = W + (size_t)(n0 + srow) * DMODEL + kt*32 + sc8;
            float4 b0 = *(const float4*)wp;
            float4 b1 = *(const float4*)(wp + 4);
            float vb[8] = {b0.x,b0.y,b0.z,b0.w,b1.x,b1.y,b1.z,b1.w};
            #pragma unroll
            for (int j = 0; j < 8; ++j) { short hh = f2bf(vb[j]); h[j] = hh; l[j] = f2bf(vb[j] - bf2f(hh)); }
            *(short8*)&Bh[srow][sc8] = h; *(short8*)&Bl[srow][sc8] = l;
        }
        __syncthreads();

        short8 ah[2], al[2], bh[2], bl[2];
        #pragma unroll
        for (int mf = 0; mf < 2; ++mf) {
            ah[mf] = *(short8*)&Ah[wm*32 + mf*16 + fr][kg*8];
            al[mf] = *(short8*)&Al[wm*32 + mf*16 + fr][kg*8];
        }
        #pragma unroll
        for (int nf = 0; nf < 2; ++nf) {
            bh[nf] = *(short8*)&Bh[wn*32 + nf*16 + fr][kg*8];
            bl[nf] = *(short8*)&Bl[wn*32 + nf*16 + fr][kg*8];
        }
        #pragma unroll
        for (int mf = 0; mf < 2; ++mf)
            #pragma unroll
            for (int nf = 0; nf < 2; ++nf) {
                acc[mf][nf] = __builtin_amdgcn_mfma_f32_16x16x32_bf16(ah[mf], bh[nf], acc[mf][nf], 0,0,0);
                acc[mf][nf] = __builtin_amdgcn_mfma_f32_16x16x32_bf16(ah[mf], bl[nf], acc[mf][nf], 0,0,0);
                acc[mf][nf] = __builtin_amdgcn_mfma_f32_16x16x32_bf16(al[mf], bh[nf], acc[mf][nf], 0,0,0);
            }
    }

    // epilogue: C/D layout col=lane&15, row=(lane>>4)*4+reg
    #pragma unroll
    for (int mf = 0; mf < 2; ++mf)
        #pragma unroll
        for (int nf = 0; nf < 2; ++nf) {
            const int col = n0 + wn*32 + nf*16 + fr;
            const float bv = bias[col];
            #pragma unroll
            for (int r = 0; r < 4; ++r) {
                const int row = m0 + wm*32 + mf*16 + kg*4 + r;
                const float o = acc[mf][nf][r] + bv;
                const size_t idx = (size_t)row * DMODEL + col;
                if (MODE == 0) {
                    Cf[idx] = o;
                } else if (MODE == 2) {
                    C0[idx] = f2bf(o);
                } else {
                    short hh = f2bf(o);
                    C0[idx] = hh;
                    C1[idx] = f2bf(o - bf2f(hh));
                }
            }
        }
}

// ---------------------------------------------------------------------------
// V transpose: vt[head][d][l] = vh[head][l][d]  (per-head [2048][64]->[64][2048])
// One WG per 64-row tile; tiny kernel (~16 MB traffic total).
// ---------------------------------------------------------------------------
__global__ __launch_bounds__(256) void vtrans_kernel(
    const short* __restrict__ vh, short* __restrict__ vt)
{
    __shared__ short T[64][72];
    const int tid = threadIdx.x;
    const int s  = blockIdx.y;          // head 0..31
    const int t0 = blockIdx.x * 64;     // row tile
    const size_t slab = (size_t)s * SLAB;

    {   // read 64x64 (coalesced 32 B / thread)
        const int r = tid >> 2, c0 = (tid & 3) << 4;
        const short* src = vh + slab + (size_t)(t0 + r) * DHD + c0;
        short8 a = *(const short8*)src;
        short8 b = *(const short8*)(src + 8);
        *(short8*)&T[r][c0]     = a;
        *(short8*)&T[r][c0 + 8] = b;
    }
    __syncthreads();
    {   // write transposed (32 B / thread)
        const int d = tid >> 2, r0 = (tid & 3) << 4;
        short8 o0, o1;
        #pragma unroll
        for (int j = 0; j < 8; ++j) { o0[j] = T[r0 + j][d]; o1[j] = T[r0 + 8 + j][d]; }
        short* dst = vt + slab + (size_t)d * LSEQ + t0 + r0;
        *(short8*)dst       = o0;
        *(short8*)(dst + 8) = o1;
    }
}

// ---------------------------------------------------------------------------
// Attention: one WG (512 thr / 8 waves) per (bh, 16-row q-tile). Single pass.
// Key structural fact: each wave's K rows (wv*16+fr) and V^T rows are DISJOINT
// across waves -> no K/V LDS staging at all; fragments load global->reg
// (L2-resident; FETCH counter proved it). Phase 1 has ZERO barriers.
// Only cross-wave traffic is the 16x128 P tile: LDS, double-buffered,
// 1 barrier per iteration.
// ---------------------------------------------------------------------------
__global__ __launch_bounds__(512, 4) void attn_kernel(
    const short* __restrict__ qh, const short* __restrict__ ql,
    const short* __restrict__ kh, const short* __restrict__ kl,
    const short* __restrict__ vt,
    float* __restrict__ attn, float* __restrict__ ctx)
{
    __shared__ __align__(16) short PB[2][16][136];   // 8,704 B  P tile (bf16), dbuf
    __shared__ __align__(16) float part[4][16][64];  // 16,384 B ctx partials
    __shared__ float redA[8][16];
    __shared__ float mrow[16], lirow[16];

    const int tid  = threadIdx.x;
    const int lane = tid & 63, wv = tid >> 6;
    const int fr = lane & 15, kg = lane >> 4;

    // head-major remap: all 128 q-tiles of head bh land on XCD (bh&7)
    const int wg  = blockIdx.x;
    const int rem = wg & 1023;
    const int q0  = (rem >> 3) << 4;               // q-tile * 16
    const int bh  = ((wg >> 10) << 3) + (rem & 7); // 0..31
    const size_t slab = (size_t)bh * SLAB;

    // Q fragments (A-operand rows q0+fr), replicated across waves
    short8 qfh[2], qfl[2];
    #pragma unroll
    for (int ks = 0; ks < 2; ++ks) {
        const size_t off = slab + (size_t)(q0 + fr) * DHD + ks*32 + kg*8;
        qfh[ks] = *(const short8*)(qh + off);
        qfl[ks] = *(const short8*)(ql + off);
    }

    f32x4 s[16];   // raw logit tile: rows kg*4+r, col i*128 + wv*16 + fr

    // ---- Phase 1: QK^T, direct global->reg K fragments, no barriers ----
    {
        const short* kbh = kh + slab + (size_t)(wv*16 + fr) * DHD;
        const short* kbl = kl + slab + (size_t)(wv*16 + fr) * DHD;
        #pragma unroll
        for (int i = 0; i < 16; ++i) {
            const short* ph = kbh + (size_t)i * (128 * DHD);
            const short* pl = kbl + (size_t)i * (128 * DHD);
            short8 kb0 = *(const short8*)(ph + kg*8);
            short8 kb1 = *(const short8*)(ph + 32 + kg*8);
            short8 kc0 = *(const short8*)(pl + kg*8);
            short8 kc1 = *(const short8*)(pl + 32 + kg*8);

            f32x4 a = {0.f,0.f,0.f,0.f};
            a = __builtin_amdgcn_mfma_f32_16x16x32_bf16(qfh[0], kb0, a, 0,0,0);
            a = __builtin_amdgcn_mfma_f32_16x16x32_bf16(qfh[1], kb1, a, 0,0,0);
            a = __builtin_amdgcn_mfma_f32_16x16x32_bf16(qfh[0], kc0, a, 0,0,0);
            a = __builtin_amdgcn_mfma_f32_16x16x32_bf16(qfh[1], kc1, a, 0,0,0);
            a = __builtin_amdgcn_mfma_f32_16x16x32_bf16(qfl[0], kb0, a, 0,0,0);
            a = __builtin_amdgcn_mfma_f32_16x16x32_bf16(qfl[1], kb1, a, 0,0,0);
            s[i] = a;
        }
    }

    // ---- deferred max ----
    f32x4 mx = s[0];
    #pragma unroll
    for (int i = 1; i < 16; ++i) {
        mx.x = fmaxf(mx.x, s[i].x); mx.y = fmaxf(mx.y, s[i].y);
        mx.z = fmaxf(mx.z, s[i].z); mx.w = fmaxf(mx.w, s[i].w);
    }
    #pragma unroll
    for (int d = 1; d < 16; d <<= 1) {
        mx.x = fmaxf(mx.x, __shfl_xor(mx.x, d));
        mx.y = fmaxf(mx.y, __shfl_xor(mx.y, d));
        mx.z = fmaxf(mx.z, __shfl_xor(mx.z, d));
        mx.w = fmaxf(mx.w, __shfl_xor(mx.w, d));
    }
    if (fr == 0) {
        redA[wv][kg*4+0] = mx.x; redA[wv][kg*4+1] = mx.y;
        redA[wv][kg*4+2] = mx.z; redA[wv][kg*4+3] = mx.w;
    }
    __syncthreads();
    if (tid < 16) {
        float m = redA[0][tid];
        #pragma unroll
        for (int w = 1; w < 8; ++w) m = fmaxf(m, redA[w][tid]);
        mrow[tid] = m;
    }
    __syncthreads();
    f32x4 m4 = { mrow[kg*4+0], mrow[kg*4+1], mrow[kg*4+2], mrow[kg*4+3] };

    // ---- exp sweep (SCALE=8 folded into log2e) + sum ----
    const float C = 8.0f * 1.44269504089f;
    f32x4 sum = {0.f,0.f,0.f,0.f};
    #pragma unroll
    for (int i = 0; i < 16; ++i) {
        f32x4 p;
        p.x = exp2f((s[i].x - m4.x) * C);
        p.y = exp2f((s[i].y - m4.y) * C);
        p.z = exp2f((s[i].z - m4.z) * C);
        p.w = exp2f((s[i].w - m4.w) * C);
        s[i] = p;
        sum.x += p.x; sum.y += p.y; sum.z += p.z; sum.w += p.w;
    }
    #pragma unroll
    for (int d = 1; d < 16; d <<= 1) {
        sum.x += __shfl_xor(sum.x, d); sum.y += __shfl_xor(sum.y, d);
        sum.z += __shfl_xor(sum.z, d); sum.w += __shfl_xor(sum.w, d);
    }
    if (fr == 0) {
        redA[wv][kg*4+0] = sum.x; redA[wv][kg*4+1] = sum.y;
        redA[wv][kg*4+2] = sum.z; redA[wv][kg*4+3] = sum.w;
    }
    __syncthreads();
    if (tid < 16) {
        float l = 0.f;
        #pragma unroll
        for (int w = 0; w < 8; ++w) l += redA[w][tid];
        lirow[tid] = 1.0f / l;
    }
    __syncthreads();
    f32x4 li4 = { lirow[kg*4+0], lirow[kg*4+1], lirow[kg*4+2], lirow[kg*4+3] };

    // ---- Phase 2: attn write + PV (PB dbuf, 1 barrier/iter; V^T global->reg) ----
    const int kc = wv & 3, dh = wv >> 2;   // wave = (k-chunk, d-half)
    f32x4 av0 = {0.f,0.f,0.f,0.f}, av1 = {0.f,0.f,0.f,0.f};
    float* abase = attn + ((size_t)bh * LSEQ + q0 + kg*4) * LSEQ + (wv<<4) + fr;
    const short* vt0 = vt + slab + (size_t)(dh*32 + fr) * LSEQ + kc*32 + kg*8;
    const short* vt1 = vt0 + 16 * LSEQ;

    #pragma unroll
    for (int i = 0; i < 16; ++i) {
        // B-fragments: contiguous 16 B from global V^T (L2-resident)
        short8 vb0 = *(const short8*)(vt0 + i*128);
        short8 vb1 = *(const short8*)(vt1 + i*128);

        // normalized probabilities -> attn (f32) + PB (bf16)
        f32x4 p = s[i];
        p.x *= li4.x; p.y *= li4.y; p.z *= li4.z; p.w *= li4.w;
        float* ap = abase + (size_t)i * 128;
        ap[0]      = p.x; ap[LSEQ]   = p.y;
        ap[2*LSEQ] = p.z; ap[3*LSEQ] = p.w;
        PB[i&1][kg*4+0][(wv<<4)+fr] = f2bf(p.x);
        PB[i&1][kg*4+1][(wv<<4)+fr] = f2bf(p.y);
        PB[i&1][kg*4+2][(wv<<4)+fr] = f2bf(p.z);
        PB[i&1][kg*4+3][(wv<<4)+fr] = f2bf(p.w);
        __syncthreads();

        short8 pa = *(short8*)&PB[i&1][fr][kc*32 + kg*8];
        av0 = __builtin_amdgcn_mfma_f32_16x16x32_bf16(pa, vb0, av0, 0,0,0);
        av1 = __builtin_amdgcn_mfma_f32_16x16x32_bf16(pa, vb1, av1, 0,0,0);
    }

    // ---- epilogue: 4-way k-chunk reduce via LDS ----
    {
        float* pt = (float*)part;
        const int db = dh*32;
        pt[kc*1024 + (kg*4+0)*64 + db + fr] = av0.x;
        pt[kc*1024 + (kg*4+1)*64 + db + fr] = av0.y;
        pt[kc*1024 + (kg*4+2)*64 + db + fr] = av0.z;
        pt[kc*1024 + (kg*4+3)*64 + db + fr] = av0.w;
        pt[kc*1024 + (kg*4+0)*64 + db + 16 + fr] = av1.x;
        pt[kc*1024 + (kg*4+1)*64 + db + 16 + fr] = av1.y;
        pt[kc*1024 + (kg*4+2)*64 + db + 16 + fr] = av1.z;
        pt[kc*1024 + (kg*4+3)*64 + db + 16 + fr] = av1.w;
    }
    __syncthreads();
    {
        float* pt = (float*)part;
        const int e = tid << 1;            // 512 thr x 2 floats = 16x64
        const int q = e >> 6, d = e & 63;
        float2 r2 = {0.f, 0.f};
        #pragma unroll
        for (int k4 = 0; k4 < 4; ++k4) {
            float2 t = *(float2*)(pt + k4*1024 + e);
            r2.x += t.x; r2.y += t.y;
        }
        *(float2*)(ctx + slab + (size_t)(q0 + q) * DHD + d) = r2;
    }
}

// ---------------------------------------------------------------------------
// Residual + LayerNorm: out = LN(resid + x) * gamma + beta, one row per block
// ---------------------------------------------------------------------------
__global__ __launch_bounds__(128) void ln_kernel(
    const float* __restrict__ resid, const float* __restrict__ x,
    const float* __restrict__ gamma, const float* __restrict__ beta,
    float* __restrict__ out)
{
    const int row = blockIdx.x;
    const int tid = threadIdx.x;
    const size_t base = (size_t)row * DMODEL + tid*4;

    float4 v = *(const float4*)(x + base);
    float4 rq = *(const float4*)(resid + base);
    v.x += rq.x; v.y += rq.y; v.z += rq.z; v.w += rq.w;

    float s  = v.x + v.y + v.z + v.w;
    float ss = v.x*v.x + v.y*v.y + v.z*v.z + v.w*v.w;
    #pragma unroll
    for (int d = 1; d < 64; d <<= 1) { s += __shfl_xor(s, d); ss += __shfl_xor(ss, d); }

    __shared__ float red[2][2];
    const int wv = tid >> 6;
    if ((tid & 63) == 0) { red[wv][0] = s; red[wv][1] = ss; }
    __syncthreads();
    s  = red[0][0] + red[1][0];
    ss = red[0][1] + red[1][1];

    const float mu  = s * (1.0f/512.0f);
    const float var = ss * (1.0f/512.0f) - mu*mu;
    const float rs  = rsqrtf(var + 1e-5f);

    float4 g = *(const float4*)(gamma + tid*4);
    float4 b = *(const float4*)(beta + tid*4);
    float4 o;
    o.x = (v.x - mu) * rs * g.x + b.x;
    o.y = (v.y - mu) * rs * g.y + b.y;
    o.z = (v.z - mu) * rs * g.z + b.z;
    o.w = (v.w - mu) * rs * g.w + b.w;
    *(float4*)(out + base) = o;
}

// ---------------------------------------------------------------------------
extern "C" void kernel_launch(void* const* d_in, const int* in_sizes, int n_in,
                              void* d_out, int out_size, void* d_ws, size_t ws_size,
                              hipStream_t stream)
{
    const float* query = (const float*)d_in[0];
    const float* key   = (const float*)d_in[1];
    const float* value = (const float*)d_in[2];
    const float* Wq = (const float*)d_in[3];
    const float* bq = (const float*)d_in[4];
    const float* Wk = (const float*)d_in[5];
    const float* bk = (const float*)d_in[6];
    const float* Wv = (const float*)d_in[7];
    const float* bv = (const float*)d_in[8];
    const float* Wo = (const float*)d_in[9];
    const float* bo = (const float*)d_in[10];
    const float* gamma = (const float*)d_in[11];
    const float* beta  = (const float*)d_in[12];

    float* out  = (float*)d_out;            // [B,L,D] = 4,194,304 f32
    float* attn = out + 4194304;            // [32,2048,2048] f32

    const size_t NTOK = (size_t)8192 * 512; // 4,194,304 elements
    short* qh = (short*)d_ws;               // split-bf16 projected tensors
    short* ql = qh + NTOK;
    short* kh = ql + NTOK;
    short* kl = kh + NTOK;
    short* vh = kl + NTOK;
    short* vt = vh + NTOK;                  // V^T per head [64][2048]
    // obuf aliases qh/ql (dead after attn_kernel); ws requirement = 48 MB
    float* obuf = (float*)d_ws;

    dim3 pgrid(8, 128), pblk(256);
    proj_gemm<1><<<pgrid, pblk, 0, stream>>>(query, Wq, bq, nullptr, qh, ql);
    proj_gemm<1><<<pgrid, pblk, 0, stream>>>(key,   Wk, bk, nullptr, kh, kl);
    proj_gemm<2><<<pgrid, pblk, 0, stream>>>(value, Wv, bv, nullptr, vh, nullptr);

    vtrans_kernel<<<dim3(32, 32), 256, 0, stream>>>(vh, vt);

    attn_kernel<<<4096, 512, 0, stream>>>(qh, ql, kh, kl, vt, attn, out /*ctx*/);

    proj_gemm<0><<<pgrid, pblk, 0, stream>>>(out /*ctx*/, Wo, bo, obuf, nullptr, nullptr);
    ln_kernel<<<8192, 128, 0, stream>>>(query, obuf, gamma, beta, out);
}

// Round 5
// 427.017 us; speedup vs baseline: 1.2322x; 1.2322x over previous
//
#include <hip/hip_runtime.h>

// Problem constants
#define LSEQ 2048
#define DMODEL 512
#define DHD 64          // head dim of the (faithful) raw view
#define SLAB (LSEQ*DHD) // 131072 elements per contiguous head slab

typedef __attribute__((ext_vector_type(8))) short short8;
typedef __attribute__((ext_vector_type(4))) float f32x4;

__device__ __forceinline__ short f2bf(float x) {   // round-to-nearest-even bf16
    union { float f; unsigned u; } v; v.f = x;
    unsigned r = v.u + 0x7FFF + ((v.u >> 16) & 1);
    return (short)(r >> 16);
}
__device__ __forceinline__ float bf2f(short h) {
    union { float f; unsigned u; } v; v.u = ((unsigned)(unsigned short)h) << 16;
    return v.f;
}

// direct global->LDS async copy, 16 B per lane (dest = wave-uniform base + lane*16)
#define GLOAD_LDS16(g, l) __builtin_amdgcn_global_load_lds( \
    (const __attribute__((address_space(1))) void*)(g),     \
    (__attribute__((address_space(3))) void*)(l), 16, 0, 0)

// ---------------------------------------------------------------------------
// Projection GEMM: C[8192,512] = A[8192,512] @ W[512,512]^T + bias
// MODE 0: write f32 Cf; MODE 1: write split hi/lo bf16 (C0,C1); MODE 2: bf16 C0
// Split-f32 precision: a*w ~= ah*wh + ah*wl + al*wh  (3 MFMAs)
// ---------------------------------------------------------------------------
template<int MODE>
__global__ __launch_bounds__(256) void proj_gemm(
    const float* __restrict__ A, const float* __restrict__ W,
    const float* __restrict__ bias, float* __restrict__ Cf,
    short* __restrict__ C0, short* __restrict__ C1)
{
    __shared__ __align__(16) short Ah[64][40], Al[64][40], Bh[64][40], Bl[64][40];

    const int tid  = threadIdx.x;
    const int lane = tid & 63, wv = tid >> 6;
    const int wm = wv >> 1, wn = wv & 1;
    const int fr = lane & 15, kg = lane >> 4;
    const int m0 = blockIdx.y * 64, n0 = blockIdx.x * 64;

    f32x4 acc[2][2];
    #pragma unroll
    for (int i = 0; i < 2; ++i)
        #pragma unroll
        for (int j = 0; j < 2; ++j) { f32x4 z = {0.f,0.f,0.f,0.f}; acc[i][j] = z; }

    const int srow = tid >> 2, sc8 = (tid & 3) << 3;

    for (int kt = 0; kt < 16; ++kt) {
        __syncthreads();
        {   // stage A/W tile, converting f32 -> hi/lo bf16
            const float* ap = A + (size_t)(m0 + srow) * DMODEL + kt*32 + sc8;
            float4 a0 = *(const float4*)ap;
            float4 a1 = *(const float4*)(ap + 4);
            float va[8] = {a0.x,a0.y,a0.z,a0.w,a1.x,a1.y,a1.z,a1.w};
            short8 h, l;
            #pragma unroll
            for (int j = 0; j < 8; ++j) { short hh = f2bf(va[j]); h[j] = hh; l[j] = f2bf(va[j] - bf2f(hh)); }
            *(short8*)&Ah[srow][sc8] = h; *(short8*)&Al[srow][sc8] = l;

            const float* wp = W + (size_t)(n0 + srow) * DMODEL + kt*32 + sc8;
            float4 b0 = *(const float4*)wp;
            float4 b1 = *(const float4*)(wp + 4);
            float vb[8] = {b0.x,b0.y,b0.z,b0.w,b1.x,b1.y,b1.z,b1.w};
            #pragma unroll
            for (int j = 0; j < 8; ++j) { short hh = f2bf(vb[j]); h[j] = hh; l[j] = f2bf(vb[j] - bf2f(hh)); }
            *(short8*)&Bh[srow][sc8] = h; *(short8*)&Bl[srow][sc8] = l;
        }
        __syncthreads();

        short8 ah[2], al[2], bh[2], bl[2];
        #pragma unroll
        for (int mf = 0; mf < 2; ++mf) {
            ah[mf] = *(short8*)&Ah[wm*32 + mf*16 + fr][kg*8];
            al[mf] = *(short8*)&Al[wm*32 + mf*16 + fr][kg*8];
        }
        #pragma unroll
        for (int nf = 0; nf < 2; ++nf) {
            bh[nf] = *(short8*)&Bh[wn*32 + nf*16 + fr][kg*8];
            bl[nf] = *(short8*)&Bl[wn*32 + nf*16 + fr][kg*8];
        }
        #pragma unroll
        for (int mf = 0; mf < 2; ++mf)
            #pragma unroll
            for (int nf = 0; nf < 2; ++nf) {
                acc[mf][nf] = __builtin_amdgcn_mfma_f32_16x16x32_bf16(ah[mf], bh[nf], acc[mf][nf], 0,0,0);
                acc[mf][nf] = __builtin_amdgcn_mfma_f32_16x16x32_bf16(ah[mf], bl[nf], acc[mf][nf], 0,0,0);
                acc[mf][nf] = __builtin_amdgcn_mfma_f32_16x16x32_bf16(al[mf], bh[nf], acc[mf][nf], 0,0,0);
            }
    }

    // epilogue: C/D layout col=lane&15, row=(lane>>4)*4+reg
    #pragma unroll
    for (int mf = 0; mf < 2; ++mf)
        #pragma unroll
        for (int nf = 0; nf < 2; ++nf) {
            const int col = n0 + wn*32 + nf*16 + fr;
            const float bv = bias[col];
            #pragma unroll
            for (int r = 0; r < 4; ++r) {
                const int row = m0 + wm*32 + mf*16 + kg*4 + r;
                const float o = acc[mf][nf][r] + bv;
                const size_t idx = (size_t)row * DMODEL + col;
                if (MODE == 0) {
                    Cf[idx] = o;
                } else if (MODE == 2) {
                    C0[idx] = f2bf(o);
                } else {
                    short hh = f2bf(o);
                    C0[idx] = hh;
                    C1[idx] = f2bf(o - bf2f(hh));
                }
            }
        }
}

// ---------------------------------------------------------------------------
// V transpose: vt[head][d][l] = vh[head][l][d]  (per-head [2048][64]->[64][2048])
// ---------------------------------------------------------------------------
__global__ __launch_bounds__(256) void vtrans_kernel(
    const short* __restrict__ vh, short* __restrict__ vt)
{
    __shared__ short T[64][72];
    const int tid = threadIdx.x;
    const int s  = blockIdx.y;          // head 0..31
    const int t0 = blockIdx.x * 64;     // row tile
    const size_t slab = (size_t)s * SLAB;

    {   // read 64x64 (coalesced 32 B / thread)
        const int r = tid >> 2, c0 = (tid & 3) << 4;
        const short* src = vh + slab + (size_t)(t0 + r) * DHD + c0;
        short8 a = *(const short8*)src;
        short8 b = *(const short8*)(src + 8);
        *(short8*)&T[r][c0]     = a;
        *(short8*)&T[r][c0 + 8] = b;
    }
    __syncthreads();
    {   // write transposed (32 B / thread)
        const int d = tid >> 2, r0 = (tid & 3) << 4;
        short8 o0, o1;
        #pragma unroll
        for (int j = 0; j < 8; ++j) { o0[j] = T[r0 + j][d]; o1[j] = T[r0 + 8 + j][d]; }
        short* dst = vt + slab + (size_t)d * LSEQ + t0 + r0;
        *(short8*)dst       = o0;
        *(short8*)(dst + 8) = o1;
    }
}

// ---------------------------------------------------------------------------
// Attention: one WG (512 thr / 8 waves) per (bh, 16-row q-tile). Single pass.
// HYBRID of measured-best pieces:
//   Phase 1 (round-3): K staged via swizzled-source global_load_lds (wave-
//     coalesced 1KB/instr), LDS broadcast reads, 2 barriers/iter.  [350us phase1]
//   Phase 2 (round-4): V from pre-transposed global vt (L2-resident, no LDS
//     transpose -> no bank conflicts), PB dbuf, 1 barrier/iter.
// Epilogue partials alias the K LDS buffer. Total LDS ~42 KB.
// ---------------------------------------------------------------------------
__global__ __launch_bounds__(512, 4) void attn_kernel(
    const short* __restrict__ qh, const short* __restrict__ ql,
    const short* __restrict__ kh, const short* __restrict__ kl,
    const short* __restrict__ vt,
    float* __restrict__ attn, float* __restrict__ ctx)
{
    __shared__ __align__(16) char  KBraw[32768];     // K tile hi[0,16K) lo[16K,32K); aliased as part[] in epilogue
    __shared__ __align__(16) short PB[2][16][136];   // 8,704 B  P tile (bf16), dbuf
    __shared__ float redA[8][16];
    __shared__ float mrow[16], lirow[16];

    const int tid  = threadIdx.x;
    const int lane = tid & 63, wv = tid >> 6;
    const int fr = lane & 15, kg = lane >> 4;

    // head-major remap: all 128 q-tiles of head bh land on XCD (bh&7)
    const int wg  = blockIdx.x;
    const int rem = wg & 1023;
    const int q0  = (rem >> 3) << 4;               // q-tile * 16
    const int bh  = ((wg >> 10) << 3) + (rem & 7); // 0..31
    const size_t slab = (size_t)bh * SLAB;

    // Q fragments (A-operand rows q0+fr), replicated across waves
    short8 qfh[2], qfl[2];
    #pragma unroll
    for (int ks = 0; ks < 2; ++ks) {
        const size_t off = slab + (size_t)(q0 + fr) * DHD + ks*32 + kg*8;
        qfh[ks] = *(const short8*)(qh + off);
        qfl[ks] = *(const short8*)(ql + off);
    }

    const int srow = lane >> 3;     // staging: row within 8-row block
    const int cb0  = lane & 7;      // staging: 16B col-block

    f32x4 s[16];   // raw logit tile: rows kg*4+r, col i*128 + wv*16 + fr

    // ---- Phase 1: QK^T via LDS-staged K (swizzled source, linear dest) ----
    #pragma unroll
    for (int i = 0; i < 16; ++i) {
        __syncthreads();            // prior iter's LDS reads done
        #pragma unroll
        for (int j = 0; j < 4; ++j) {
            const int b   = wv*4 + j;            // 0..31 1KB-blocks
            const int row = ((b & 15) << 3) + srow;
            const int scb = cb0 ^ (row & 7);     // pre-swizzled global source
            const short* gp = ((b >> 4) ? kl : kh) + slab
                            + (size_t)(i*128 + row) * DHD + scb*8;
            GLOAD_LDS16(gp, KBraw + b*1024);
        }
        __syncthreads();            // staging landed (compiler drains vmcnt)

        const int klo = (wv << 4) + fr;          // tile-local K row 0..127
        const int sw  = klo & 7;
        const char* rp = KBraw + (klo << 7);
        short8 kb0 = *(short8*)(rp + ((kg ^ sw) << 4));
        short8 kb1 = *(short8*)(rp + (((4 + kg) ^ sw) << 4));
        short8 kc0 = *(short8*)(rp + 16384 + ((kg ^ sw) << 4));
        short8 kc1 = *(short8*)(rp + 16384 + (((4 + kg) ^ sw) << 4));

        f32x4 a = {0.f,0.f,0.f,0.f};
        a = __builtin_amdgcn_mfma_f32_16x16x32_bf16(qfh[0], kb0, a, 0,0,0);
        a = __builtin_amdgcn_mfma_f32_16x16x32_bf16(qfh[1], kb1, a, 0,0,0);
        a = __builtin_amdgcn_mfma_f32_16x16x32_bf16(qfh[0], kc0, a, 0,0,0);
        a = __builtin_amdgcn_mfma_f32_16x16x32_bf16(qfh[1], kc1, a, 0,0,0);
        a = __builtin_amdgcn_mfma_f32_16x16x32_bf16(qfl[0], kb0, a, 0,0,0);
        a = __builtin_amdgcn_mfma_f32_16x16x32_bf16(qfl[1], kb1, a, 0,0,0);
        s[i] = a;
    }

    // ---- deferred max ----
    f32x4 mx = s[0];
    #pragma unroll
    for (int i = 1; i < 16; ++i) {
        mx.x = fmaxf(mx.x, s[i].x); mx.y = fmaxf(mx.y, s[i].y);
        mx.z = fmaxf(mx.z, s[i].z); mx.w = fmaxf(mx.w, s[i].w);
    }
    #pragma unroll
    for (int d = 1; d < 16; d <<= 1) {
        mx.x = fmaxf(mx.x, __shfl_xor(mx.x, d));
        mx.y = fmaxf(mx.y, __shfl_xor(mx.y, d));
        mx.z = fmaxf(mx.z, __shfl_xor(mx.z, d));
        mx.w = fmaxf(mx.w, __shfl_xor(mx.w, d));
    }
    if (fr == 0) {
        redA[wv][kg*4+0] = mx.x; redA[wv][kg*4+1] = mx.y;
        redA[wv][kg*4+2] = mx.z; redA[wv][kg*4+3] = mx.w;
    }
    __syncthreads();
    if (tid < 16) {
        float m = redA[0][tid];
        #pragma unroll
        for (int w = 1; w < 8; ++w) m = fmaxf(m, redA[w][tid]);
        mrow[tid] = m;
    }
    __syncthreads();
    f32x4 m4 = { mrow[kg*4+0], mrow[kg*4+1], mrow[kg*4+2], mrow[kg*4+3] };

    // ---- exp sweep (SCALE=8 folded into log2e) + sum ----
    const float C = 8.0f * 1.44269504089f;
    f32x4 sum = {0.f,0.f,0.f,0.f};
    #pragma unroll
    for (int i = 0; i < 16; ++i) {
        f32x4 p;
        p.x = exp2f((s[i].x - m4.x) * C);
        p.y = exp2f((s[i].y - m4.y) * C);
        p.z = exp2f((s[i].z - m4.z) * C);
        p.w = exp2f((s[i].w - m4.w) * C);
        s[i] = p;
        sum.x += p.x; sum.y += p.y; sum.z += p.z; sum.w += p.w;
    }
    #pragma unroll
    for (int d = 1; d < 16; d <<= 1) {
        sum.x += __shfl_xor(sum.x, d); sum.y += __shfl_xor(sum.y, d);
        sum.z += __shfl_xor(sum.z, d); sum.w += __shfl_xor(sum.w, d);
    }
    if (fr == 0) {
        redA[wv][kg*4+0] = sum.x; redA[wv][kg*4+1] = sum.y;
        redA[wv][kg*4+2] = sum.z; redA[wv][kg*4+3] = sum.w;
    }
    __syncthreads();
    if (tid < 16) {
        float l = 0.f;
        #pragma unroll
        for (int w = 0; w < 8; ++w) l += redA[w][tid];
        lirow[tid] = 1.0f / l;
    }
    __syncthreads();
    f32x4 li4 = { lirow[kg*4+0], lirow[kg*4+1], lirow[kg*4+2], lirow[kg*4+3] };

    // ---- Phase 2: attn write + PV (PB dbuf, 1 barrier/iter; V^T global->reg) ----
    const int kc = wv & 3, dh = wv >> 2;   // wave = (k-chunk, d-half)
    f32x4 av0 = {0.f,0.f,0.f,0.f}, av1 = {0.f,0.f,0.f,0.f};
    float* abase = attn + ((size_t)bh * LSEQ + q0 + kg*4) * LSEQ + (wv<<4) + fr;
    const short* vt0 = vt + slab + (size_t)(dh*32 + fr) * LSEQ + kc*32 + kg*8;
    const short* vt1 = vt0 + 16 * LSEQ;

    #pragma unroll
    for (int i = 0; i < 16; ++i) {
        // B-fragments: contiguous 16 B from global V^T (L2-resident)
        short8 vb0 = *(const short8*)(vt0 + i*128);
        short8 vb1 = *(const short8*)(vt1 + i*128);

        // normalized probabilities -> attn (f32) + PB (bf16)
        f32x4 p = s[i];
        p.x *= li4.x; p.y *= li4.y; p.z *= li4.z; p.w *= li4.w;
        float* ap = abase + (size_t)i * 128;
        ap[0]      = p.x; ap[LSEQ]   = p.y;
        ap[2*LSEQ] = p.z; ap[3*LSEQ] = p.w;
        PB[i&1][kg*4+0][(wv<<4)+fr] = f2bf(p.x);
        PB[i&1][kg*4+1][(wv<<4)+fr] = f2bf(p.y);
        PB[i&1][kg*4+2][(wv<<4)+fr] = f2bf(p.z);
        PB[i&1][kg*4+3][(wv<<4)+fr] = f2bf(p.w);
        __syncthreads();

        short8 pa = *(short8*)&PB[i&1][fr][kc*32 + kg*8];
        av0 = __builtin_amdgcn_mfma_f32_16x16x32_bf16(pa, vb0, av0, 0,0,0);
        av1 = __builtin_amdgcn_mfma_f32_16x16x32_bf16(pa, vb1, av1, 0,0,0);
    }

    // ---- epilogue: 4-way k-chunk reduce via LDS (aliases K buffer) ----
    {
        float* pt = (float*)KBraw;     // [4][16][64] f32 partials
        const int db = dh*32;
        pt[kc*1024 + (kg*4+0)*64 + db + fr] = av0.x;
        pt[kc*1024 + (kg*4+1)*64 + db + fr] = av0.y;
        pt[kc*1024 + (kg*4+2)*64 + db + fr] = av0.z;
        pt[kc*1024 + (kg*4+3)*64 + db + fr] = av0.w;
        pt[kc*1024 + (kg*4+0)*64 + db + 16 + fr] = av1.x;
        pt[kc*1024 + (kg*4+1)*64 + db + 16 + fr] = av1.y;
        pt[kc*1024 + (kg*4+2)*64 + db + 16 + fr] = av1.z;
        pt[kc*1024 + (kg*4+3)*64 + db + 16 + fr] = av1.w;
    }
    __syncthreads();
    {
        float* pt = (float*)KBraw;
        const int e = tid << 1;            // 512 thr x 2 floats = 16x64
        const int q = e >> 6, d = e & 63;
        float2 r2 = {0.f, 0.f};
        #pragma unroll
        for (int k4 = 0; k4 < 4; ++k4) {
            float2 t = *(float2*)(pt + k4*1024 + e);
            r2.x += t.x; r2.y += t.y;
        }
        *(float2*)(ctx + slab + (size_t)(q0 + q) * DHD + d) = r2;
    }
}

// ---------------------------------------------------------------------------
// Residual + LayerNorm: out = LN(resid + x) * gamma + beta, one row per block
// ---------------------------------------------------------------------------
__global__ __launch_bounds__(128) void ln_kernel(
    const float* __restrict__ resid, const float* __restrict__ x,
    const float* __restrict__ gamma, const float* __restrict__ beta,
    float* __restrict__ out)
{
    const int row = blockIdx.x;
    const int tid = threadIdx.x;
    const size_t base = (size_t)row * DMODEL + tid*4;

    float4 v = *(const float4*)(x + base);
    float4 rq = *(const float4*)(resid + base);
    v.x += rq.x; v.y += rq.y; v.z += rq.z; v.w += rq.w;

    float s  = v.x + v.y + v.z + v.w;
    float ss = v.x*v.x + v.y*v.y + v.z*v.z + v.w*v.w;
    #pragma unroll
    for (int d = 1; d < 64; d <<= 1) { s += __shfl_xor(s, d); ss += __shfl_xor(ss, d); }

    __shared__ float red[2][2];
    const int wv = tid >> 6;
    if ((tid & 63) == 0) { red[wv][0] = s; red[wv][1] = ss; }
    __syncthreads();
    s  = red[0][0] + red[1][0];
    ss = red[0][1] + red[1][1];

    const float mu  = s * (1.0f/512.0f);
    const float var = ss * (1.0f/512.0f) - mu*mu;
    const float rs  = rsqrtf(var + 1e-5f);

    float4 g = *(const float4*)(gamma + tid*4);
    float4 b = *(const float4*)(beta + tid*4);
    float4 o;
    o.x = (v.x - mu) * rs * g.x + b.x;
    o.y = (v.y - mu) * rs * g.y + b.y;
    o.z = (v.z - mu) * rs * g.z + b.z;
    o.w = (v.w - mu) * rs * g.w + b.w;
    *(float4*)(out + base) = o;
}

// ---------------------------------------------------------------------------
extern "C" void kernel_launch(void* const* d_in, const int* in_sizes, int n_in,
                              void* d_out, int out_size, void* d_ws, size_t ws_size,
                              hipStream_t stream)
{
    const float* query = (const float*)d_in[0];
    const float* key   = (const float*)d_in[1];
    const float* value = (const float*)d_in[2];
    const float* Wq = (const float*)d_in[3];
    const float* bq = (const float*)d_in[4];
    const float* Wk = (const float*)d_in[5];
    const float* bk = (const float*)d_in[6];
    const float* Wv = (const float*)d_in[7];
    const float* bv = (const float*)d_in[8];
    const float* Wo = (const float*)d_in[9];
    const float* bo = (const float*)d_in[10];
    const float* gamma = (const float*)d_in[11];
    const float* beta  = (const float*)d_in[12];

    float* out  = (float*)d_out;            // [B,L,D] = 4,194,304 f32
    float* attn = out + 4194304;            // [32,2048,2048] f32

    const size_t NTOK = (size_t)8192 * 512; // 4,194,304 elements
    short* qh = (short*)d_ws;               // split-bf16 projected tensors
    short* ql = qh + NTOK;
    short* kh = ql + NTOK;
    short* kl = kh + NTOK;
    short* vh = kl + NTOK;
    short* vt = vh + NTOK;                  // V^T per head [64][2048]
    // obuf aliases qh/ql (dead after attn_kernel); ws requirement = 48 MB
    float* obuf = (float*)d_ws;

    dim3 pgrid(8, 128), pblk(256);
    proj_gemm<1><<<pgrid, pblk, 0, stream>>>(query, Wq, bq, nullptr, qh, ql);
    proj_gemm<1><<<pgrid, pblk, 0, stream>>>(key,   Wk, bk, nullptr, kh, kl);
    proj_gemm<2><<<pgrid, pblk, 0, stream>>>(value, Wv, bv, nullptr, vh, nullptr);

    vtrans_kernel<<<dim3(32, 32), 256, 0, stream>>>(vh, vt);

    attn_kernel<<<4096, 512, 0, stream>>>(qh, ql, kh, kl, vt, attn, out /*ctx*/);

    proj_gemm<0><<<pgrid, pblk, 0, stream>>>(out /*ctx*/, Wo, bo, obuf, nullptr, nullptr);
    ln_kernel<<<8192, 128, 0, stream>>>(query, obuf, gamma, beta, out);
}

// Round 6
// 370.953 us; speedup vs baseline: 1.4184x; 1.1511x over previous
//
#include <hip/hip_runtime.h>

// Problem constants
#define LSEQ 2048
#define DMODEL 512
#define DHD 64          // head dim of the (faithful) raw view
#define SLAB (LSEQ*DHD) // 131072 elements per contiguous head slab

typedef __attribute__((ext_vector_type(8))) short short8;
typedef __attribute__((ext_vector_type(4))) float f32x4;
typedef _Float16 half8 __attribute__((ext_vector_type(8)));
typedef _Float16 half4v __attribute__((ext_vector_type(4)));

__device__ __forceinline__ short f2bf(float x) {   // round-to-nearest-even bf16
    union { float f; unsigned u; } v; v.f = x;
    unsigned r = v.u + 0x7FFF + ((v.u >> 16) & 1);
    return (short)(r >> 16);
}
__device__ __forceinline__ float bf2f(short h) {
    union { float f; unsigned u; } v; v.u = ((unsigned)(unsigned short)h) << 16;
    return v.f;
}

// direct global->LDS async copy, 16 B per lane (dest = wave-uniform base + lane*16)
#define GLOAD_LDS16(g, l) __builtin_amdgcn_global_load_lds( \
    (const __attribute__((address_space(1))) void*)(g),     \
    (__attribute__((address_space(3))) void*)(l), 16, 0, 0)

#define VMCNT0()  asm volatile("s_waitcnt vmcnt(0)" ::: "memory")
#define LGKM0()   asm volatile("s_waitcnt lgkmcnt(0)" ::: "memory")
#define BARRIER() do { __builtin_amdgcn_s_barrier(); __builtin_amdgcn_sched_barrier(0); } while (0)

// ---------------------------------------------------------------------------
// Projection GEMM: C[8192,512] = A[8192,512] @ W[512,512]^T + bias
// Internally split-f32 precision: a*w ~= ah*wh + ah*wl + al*wh (3 bf16 MFMAs).
// MODE 0: write f32 Cf.   MODE 3: write f16 C0 (round once at the end).
// ---------------------------------------------------------------------------
template<int MODE>
__global__ __launch_bounds__(256) void proj_gemm(
    const float* __restrict__ A, const float* __restrict__ W,
    const float* __restrict__ bias, float* __restrict__ Cf,
    short* __restrict__ C0)
{
    __shared__ __align__(16) short Ah[64][40], Al[64][40], Bh[64][40], Bl[64][40];

    const int tid  = threadIdx.x;
    const int lane = tid & 63, wv = tid >> 6;
    const int wm = wv >> 1, wn = wv & 1;
    const int fr = lane & 15, kg = lane >> 4;
    const int m0 = blockIdx.y * 64, n0 = blockIdx.x * 64;

    f32x4 acc[2][2];
    #pragma unroll
    for (int i = 0; i < 2; ++i)
        #pragma unroll
        for (int j = 0; j < 2; ++j) { f32x4 z = {0.f,0.f,0.f,0.f}; acc[i][j] = z; }

    const int srow = tid >> 2, sc8 = (tid & 3) << 3;

    for (int kt = 0; kt < 16; ++kt) {
        __syncthreads();
        {   // stage A/W tile, converting f32 -> hi/lo bf16
            const float* ap = A + (size_t)(m0 + srow) * DMODEL + kt*32 + sc8;
            float4 a0 = *(const float4*)ap;
            float4 a1 = *(const float4*)(ap + 4);
            float va[8] = {a0.x,a0.y,a0.z,a0.w,a1.x,a1.y,a1.z,a1.w};
            short8 h, l;
            #pragma unroll
            for (int j = 0; j < 8; ++j) { short hh = f2bf(va[j]); h[j] = hh; l[j] = f2bf(va[j] - bf2f(hh)); }
            *(short8*)&Ah[srow][sc8] = h; *(short8*)&Al[srow][sc8] = l;

            const float* wp = W + (size_t)(n0 + srow) * DMODEL + kt*32 + sc8;
            float4 b0 = *(const float4*)wp;
            float4 b1 = *(const float4*)(wp + 4);
            float vb[8] = {b0.x,b0.y,b0.z,b0.w,b1.x,b1.y,b1.z,b1.w};
            #pragma unroll
            for (int j = 0; j < 8; ++j) { short hh = f2bf(vb[j]); h[j] = hh; l[j] = f2bf(vb[j] - bf2f(hh)); }
            *(short8*)&Bh[srow][sc8] = h; *(short8*)&Bl[srow][sc8] = l;
        }
        __syncthreads();

        short8 ah[2], al[2], bh[2], bl[2];
        #pragma unroll
        for (int mf = 0; mf < 2; ++mf) {
            ah[mf] = *(short8*)&Ah[wm*32 + mf*16 + fr][kg*8];
            al[mf] = *(short8*)&Al[wm*32 + mf*16 + fr][kg*8];
        }
        #pragma unroll
        for (int nf = 0; nf < 2; ++nf) {
            bh[nf] = *(short8*)&Bh[wn*32 + nf*16 + fr][kg*8];
            bl[nf] = *(short8*)&Bl[wn*32 + nf*16 + fr][kg*8];
        }
        #pragma unroll
        for (int mf = 0; mf < 2; ++mf)
            #pragma unroll
            for (int nf = 0; nf < 2; ++nf) {
                acc[mf][nf] = __builtin_amdgcn_mfma_f32_16x16x32_bf16(ah[mf], bh[nf], acc[mf][nf], 0,0,0);
                acc[mf][nf] = __builtin_amdgcn_mfma_f32_16x16x32_bf16(ah[mf], bl[nf], acc[mf][nf], 0,0,0);
                acc[mf][nf] = __builtin_amdgcn_mfma_f32_16x16x32_bf16(al[mf], bh[nf], acc[mf][nf], 0,0,0);
            }
    }

    // epilogue: C/D layout col=lane&15, row=(lane>>4)*4+reg
    #pragma unroll
    for (int mf = 0; mf < 2; ++mf)
        #pragma unroll
        for (int nf = 0; nf < 2; ++nf) {
            const int col = n0 + wn*32 + nf*16 + fr;
            const float bv = bias[col];
            #pragma unroll
            for (int r = 0; r < 4; ++r) {
                const int row = m0 + wm*32 + mf*16 + kg*4 + r;
                const float o = acc[mf][nf][r] + bv;
                const size_t idx = (size_t)row * DMODEL + col;
                if (MODE == 0) Cf[idx] = o;
                else           ((_Float16*)C0)[idx] = (_Float16)o;
            }
        }
}

// ---------------------------------------------------------------------------
// V transpose: vt[head][d][l] = vf[head][l][d]  (f16, per-head [2048][64]->[64][2048])
// ---------------------------------------------------------------------------
__global__ __launch_bounds__(256) void vtrans_kernel(
    const short* __restrict__ vh, short* __restrict__ vt)
{
    __shared__ short T[64][72];
    const int tid = threadIdx.x;
    const int s  = blockIdx.y;          // head 0..31
    const int t0 = blockIdx.x * 64;     // row tile
    const size_t slab = (size_t)s * SLAB;

    {   // read 64x64 (coalesced 32 B / thread)
        const int r = tid >> 2, c0 = (tid & 3) << 4;
        const short* src = vh + slab + (size_t)(t0 + r) * DHD + c0;
        short8 a = *(const short8*)src;
        short8 b = *(const short8*)(src + 8);
        *(short8*)&T[r][c0]     = a;
        *(short8*)&T[r][c0 + 8] = b;
    }
    __syncthreads();
    {   // write transposed (32 B / thread)
        const int d = tid >> 2, r0 = (tid & 3) << 4;
        short8 o0, o1;
        #pragma unroll
        for (int j = 0; j < 8; ++j) { o0[j] = T[r0 + j][d]; o1[j] = T[r0 + 8 + j][d]; }
        short* dst = vt + slab + (size_t)d * LSEQ + t0 + r0;
        *(short8*)dst       = o0;
        *(short8*)(dst + 8) = o1;
    }
}

// ---------------------------------------------------------------------------
// Attention, f16 single-precision QK^T/PV (projections were split-f32 accurate):
//   Phase 1: K staged via swizzled-source global_load_lds into a DOUBLE-
//     BUFFERED 16 KB tile, T3 minimum-2-phase schedule with raw s_barrier +
//     explicit counted waits (no compiler vmcnt(0) store drains).
//   Phase 2: V^T from global (L2-resident), register-prefetched one tile
//     ahead; P tile in LDS (f16, dbuf); attn stored via PB as dwordx4.
// LDS ~41 KB, VGPR ~120 -> 2 WGs/CU.
// ---------------------------------------------------------------------------
__global__ __launch_bounds__(512, 4) void attn_kernel(
    const _Float16* __restrict__ qf, const _Float16* __restrict__ kf,
    const _Float16* __restrict__ vt,
    float* __restrict__ attn, float* __restrict__ ctx)
{
    __shared__ __align__(16) _Float16 KB[2][8192];     // 2 x 16 KB K tile (128 rows x 64 f16)
    __shared__ __align__(16) _Float16 PB[2][16][136];  // 8,704 B P tile, dbuf
    __shared__ float redA[8][16];
    __shared__ float mrow[16], lirow[16];

    const int tid  = threadIdx.x;
    const int lane = tid & 63, wv = tid >> 6;
    const int fr = lane & 15, kg = lane >> 4;

    // head-major remap: all 128 q-tiles of head bh land on XCD (bh&7)
    const int wg  = blockIdx.x;
    const int rem = wg & 1023;
    const int q0  = (rem >> 3) << 4;               // q-tile * 16
    const int bh  = ((wg >> 10) << 3) + (rem & 7); // 0..31
    const size_t slab = (size_t)bh * SLAB;

    // Q fragments (A-operand rows q0+fr), replicated across waves
    half8 qa[2];
    #pragma unroll
    for (int ks = 0; ks < 2; ++ks)
        qa[ks] = *(const half8*)(qf + slab + (size_t)(q0 + fr) * DHD + ks*32 + kg*8);

    const int srow = lane >> 3;     // staging: row within 8-row block
    const int scb  = (lane & 7) ^ srow;  // pre-swizzled global 16B col-block

    f32x4 s[16];   // raw logit tile: rows kg*4+r, col i*128 + wv*16 + fr

    // ---- Phase 1: QK^T, dbuf'd K staging, raw-barrier 2-phase schedule ----
    #define STAGE_K(TI, CUR) { \
        for (int j = 0; j < 2; ++j) { \
            const int b = wv*2 + j; \
            GLOAD_LDS16(kf + slab + (size_t)((TI)*128 + b*8 + srow)*DHD + scb*8, \
                        (char*)&KB[CUR][0] + b*1024); \
        } }

    STAGE_K(0, 0);
    VMCNT0();
    BARRIER();

    const int klo = (wv << 4) + fr;          // tile-local K row 0..127
    const int sw  = fr & 7;                  // klo & 7
    int cur = 0;
    #pragma unroll
    for (int i = 0; i < 16; ++i) {
        if (i < 15) STAGE_K(i+1, cur^1);     // issue next-tile loads first

        const char* rp = (const char*)&KB[cur][0] + (klo << 7);
        half8 kb0 = *(const half8*)(rp + ((kg ^ sw) << 4));
        half8 kb1 = *(const half8*)(rp + (((4 + kg) ^ sw) << 4));

        f32x4 a = {0.f,0.f,0.f,0.f};
        a = __builtin_amdgcn_mfma_f32_16x16x32_f16(qa[0], kb0, a, 0,0,0);
        a = __builtin_amdgcn_mfma_f32_16x16x32_f16(qa[1], kb1, a, 0,0,0);
        s[i] = a;

        VMCNT0();                            // next tile landed (2 loads)
        BARRIER();                           // everyone done with cur + has next
        cur ^= 1;
    }
    #undef STAGE_K

    // ---- deferred max ----
    f32x4 mx = s[0];
    #pragma unroll
    for (int i = 1; i < 16; ++i) {
        mx.x = fmaxf(mx.x, s[i].x); mx.y = fmaxf(mx.y, s[i].y);
        mx.z = fmaxf(mx.z, s[i].z); mx.w = fmaxf(mx.w, s[i].w);
    }
    #pragma unroll
    for (int d = 1; d < 16; d <<= 1) {
        mx.x = fmaxf(mx.x, __shfl_xor(mx.x, d));
        mx.y = fmaxf(mx.y, __shfl_xor(mx.y, d));
        mx.z = fmaxf(mx.z, __shfl_xor(mx.z, d));
        mx.w = fmaxf(mx.w, __shfl_xor(mx.w, d));
    }
    if (fr == 0) {
        redA[wv][kg*4+0] = mx.x; redA[wv][kg*4+1] = mx.y;
        redA[wv][kg*4+2] = mx.z; redA[wv][kg*4+3] = mx.w;
    }
    __syncthreads();
    if (tid < 16) {
        float m = redA[0][tid];
        #pragma unroll
        for (int w = 1; w < 8; ++w) m = fmaxf(m, redA[w][tid]);
        mrow[tid] = m;
    }
    __syncthreads();
    f32x4 m4 = { mrow[kg*4+0], mrow[kg*4+1], mrow[kg*4+2], mrow[kg*4+3] };

    // ---- exp sweep (SCALE=8 folded into log2e) + sum ----
    const float C = 8.0f * 1.44269504089f;
    f32x4 sum = {0.f,0.f,0.f,0.f};
    #pragma unroll
    for (int i = 0; i < 16; ++i) {
        f32x4 p;
        p.x = exp2f((s[i].x - m4.x) * C);
        p.y = exp2f((s[i].y - m4.y) * C);
        p.z = exp2f((s[i].z - m4.z) * C);
        p.w = exp2f((s[i].w - m4.w) * C);
        s[i] = p;
        sum.x += p.x; sum.y += p.y; sum.z += p.z; sum.w += p.w;
    }
    #pragma unroll
    for (int d = 1; d < 16; d <<= 1) {
        sum.x += __shfl_xor(sum.x, d); sum.y += __shfl_xor(sum.y, d);
        sum.z += __shfl_xor(sum.z, d); sum.w += __shfl_xor(sum.w, d);
    }
    if (fr == 0) {
        redA[wv][kg*4+0] = sum.x; redA[wv][kg*4+1] = sum.y;
        redA[wv][kg*4+2] = sum.z; redA[wv][kg*4+3] = sum.w;
    }
    __syncthreads();
    if (tid < 16) {
        float l = 0.f;
        #pragma unroll
        for (int w = 0; w < 8; ++w) l += redA[w][tid];
        lirow[tid] = 1.0f / l;
    }
    __syncthreads();
    f32x4 li4 = { lirow[kg*4+0], lirow[kg*4+1], lirow[kg*4+2], lirow[kg*4+3] };

    // ---- Phase 2: PB dbuf + PV + coalesced attn store (raw barriers) ----
    const int kc = wv & 3, dh = wv >> 2;   // wave = (k-chunk, d-half)
    f32x4 av0 = {0.f,0.f,0.f,0.f}, av1 = {0.f,0.f,0.f,0.f};
    const _Float16* vtp0 = vt + slab + (size_t)(dh*32 + fr) * LSEQ + kc*32 + kg*8;
    const _Float16* vtp1 = vtp0 + 16 * LSEQ;
    const int arow = tid >> 5, acol = (tid & 31) << 2;      // attn-store mapping
    float* abase = attn + ((size_t)bh * LSEQ + q0 + arow) * LSEQ + acol;

    half8 vb0 = *(const half8*)vtp0;
    half8 vb1 = *(const half8*)vtp1;
    cur = 0;
    #pragma unroll
    for (int i = 0; i < 16; ++i) {
        // normalized probabilities -> PB (f16)
        f32x4 p = s[i];
        p.x *= li4.x; p.y *= li4.y; p.z *= li4.z; p.w *= li4.w;
        PB[cur][kg*4+0][(wv<<4)+fr] = (_Float16)p.x;
        PB[cur][kg*4+1][(wv<<4)+fr] = (_Float16)p.y;
        PB[cur][kg*4+2][(wv<<4)+fr] = (_Float16)p.z;
        PB[cur][kg*4+3][(wv<<4)+fr] = (_Float16)p.w;
        LGKM0();                    // my PB writes visible in LDS
        BARRIER();                  // whole P tile ready

        // prefetch next V tile into registers (hidden under MFMA/stores)
        half8 nvb0, nvb1;
        if (i < 15) {
            nvb0 = *(const half8*)(vtp0 + (i+1)*128);
            nvb1 = *(const half8*)(vtp1 + (i+1)*128);
        }

        // PV
        half8 pa = *(const half8*)&PB[cur][fr][kc*32 + kg*8];
        av0 = __builtin_amdgcn_mfma_f32_16x16x32_f16(pa, vb0, av0, 0,0,0);
        av1 = __builtin_amdgcn_mfma_f32_16x16x32_f16(pa, vb1, av1, 0,0,0);

        // attn store via PB: 512 thr x 4 consecutive cols = dwordx4, 512B/wave rows
        half4v pr = *(const half4v*)&PB[cur][arow][acol];
        float4 o = { (float)pr[0], (float)pr[1], (float)pr[2], (float)pr[3] };
        *(float4*)(abase + (size_t)i * 128) = o;

        vb0 = nvb0; vb1 = nvb1;
        cur ^= 1;
    }

    // ---- epilogue: 4-way k-chunk reduce via LDS (aliases K buffer) ----
    __syncthreads();               // full drain once; KB free
    {
        float* pt = (float*)&KB[0][0];   // [4][16][64] f32 partials
        const int db = dh*32;
        pt[kc*1024 + (kg*4+0)*64 + db + fr] = av0.x;
        pt[kc*1024 + (kg*4+1)*64 + db + fr] = av0.y;
        pt[kc*1024 + (kg*4+2)*64 + db + fr] = av0.z;
        pt[kc*1024 + (kg*4+3)*64 + db + fr] = av0.w;
        pt[kc*1024 + (kg*4+0)*64 + db + 16 + fr] = av1.x;
        pt[kc*1024 + (kg*4+1)*64 + db + 16 + fr] = av1.y;
        pt[kc*1024 + (kg*4+2)*64 + db + 16 + fr] = av1.z;
        pt[kc*1024 + (kg*4+3)*64 + db + 16 + fr] = av1.w;
    }
    __syncthreads();
    {
        float* pt = (float*)&KB[0][0];
        const int e = tid << 1;            // 512 thr x 2 floats = 16x64
        const int q = e >> 6, d = e & 63;
        float2 r2 = {0.f, 0.f};
        #pragma unroll
        for (int k4 = 0; k4 < 4; ++k4) {
            float2 t = *(float2*)(pt + k4*1024 + e);
            r2.x += t.x; r2.y += t.y;
        }
        *(float2*)(ctx + slab + (size_t)(q0 + q) * DHD + d) = r2;
    }
}

// ---------------------------------------------------------------------------
// Residual + LayerNorm: out = LN(resid + x) * gamma + beta, one row per block
// ---------------------------------------------------------------------------
__global__ __launch_bounds__(128) void ln_kernel(
    const float* __restrict__ resid, const float* __restrict__ x,
    const float* __restrict__ gamma, const float* __restrict__ beta,
    float* __restrict__ out)
{
    const int row = blockIdx.x;
    const int tid = threadIdx.x;
    const size_t base = (size_t)row * DMODEL + tid*4;

    float4 v = *(const float4*)(x + base);
    float4 rq = *(const float4*)(resid + base);
    v.x += rq.x; v.y += rq.y; v.z += rq.z; v.w += rq.w;

    float s  = v.x + v.y + v.z + v.w;
    float ss = v.x*v.x + v.y*v.y + v.z*v.z + v.w*v.w;
    #pragma unroll
    for (int d = 1; d < 64; d <<= 1) { s += __shfl_xor(s, d); ss += __shfl_xor(ss, d); }

    __shared__ float red[2][2];
    const int wv = tid >> 6;
    if ((tid & 63) == 0) { red[wv][0] = s; red[wv][1] = ss; }
    __syncthreads();
    s  = red[0][0] + red[1][0];
    ss = red[0][1] + red[1][1];

    const float mu  = s * (1.0f/512.0f);
    const float var = ss * (1.0f/512.0f) - mu*mu;
    const float rs  = rsqrtf(var + 1e-5f);

    float4 g = *(const float4*)(gamma + tid*4);
    float4 b = *(const float4*)(beta + tid*4);
    float4 o;
    o.x = (v.x - mu) * rs * g.x + b.x;
    o.y = (v.y - mu) * rs * g.y + b.y;
    o.z = (v.z - mu) * rs * g.z + b.z;
    o.w = (v.w - mu) * rs * g.w + b.w;
    *(float4*)(out + base) = o;
}

// ---------------------------------------------------------------------------
extern "C" void kernel_launch(void* const* d_in, const int* in_sizes, int n_in,
                              void* d_out, int out_size, void* d_ws, size_t ws_size,
                              hipStream_t stream)
{
    const float* query = (const float*)d_in[0];
    const float* key   = (const float*)d_in[1];
    const float* value = (const float*)d_in[2];
    const float* Wq = (const float*)d_in[3];
    const float* bq = (const float*)d_in[4];
    const float* Wk = (const float*)d_in[5];
    const float* bk = (const float*)d_in[6];
    const float* Wv = (const float*)d_in[7];
    const float* bv = (const float*)d_in[8];
    const float* Wo = (const float*)d_in[9];
    const float* bo = (const float*)d_in[10];
    const float* gamma = (const float*)d_in[11];
    const float* beta  = (const float*)d_in[12];

    float* out  = (float*)d_out;            // [B,L,D] = 4,194,304 f32
    float* attn = out + 4194304;            // [32,2048,2048] f32

    const size_t NTOK = (size_t)8192 * 512; // 4,194,304 elements
    short* qv = (short*)d_ws;               // f16 projected tensors
    short* kv = qv + NTOK;
    short* vf = kv + NTOK;
    short* vt = vf + NTOK;                  // V^T per head [64][2048] f16
    // obuf aliases qv/kv (dead after attn_kernel); ws requirement = 32 MB
    float* obuf = (float*)d_ws;

    dim3 pgrid(8, 128), pblk(256);
    proj_gemm<3><<<pgrid, pblk, 0, stream>>>(query, Wq, bq, nullptr, qv);
    proj_gemm<3><<<pgrid, pblk, 0, stream>>>(key,   Wk, bk, nullptr, kv);
    proj_gemm<3><<<pgrid, pblk, 0, stream>>>(value, Wv, bv, nullptr, vf);

    vtrans_kernel<<<dim3(32, 32), 256, 0, stream>>>(vf, vt);

    attn_kernel<<<4096, 512, 0, stream>>>((const _Float16*)qv, (const _Float16*)kv,
                                          (const _Float16*)vt, attn, out /*ctx*/);

    proj_gemm<0><<<pgrid, pblk, 0, stream>>>(out /*ctx*/, Wo, bo, obuf, nullptr);
    ln_kernel<<<8192, 128, 0, stream>>>(query, obuf, gamma, beta, out);
}